// Round 11
// baseline (227.066 us; speedup 1.0000x reference)
//
#include <hip/hip_runtime.h>

#define G_N    32
#define MUL    128
#define RADII  20
#define CH     4
#define RES_B  180
#define RES_A  359
#define IDIM   36
#define COEFF_N (G_N*CH*RADII*IDIM)   // 92160 = 360*256
#define NQ     5                      // alpha chunks per (g,r)
#define PW     36                     // alpha-pairs per block (5*36 = 180)

typedef float v2f __attribute__((ext_vector_type(2)));

__device__ __forceinline__ float fexp2(float x){
#if __has_builtin(__builtin_amdgcn_exp2f)
  return __builtin_amdgcn_exp2f(x);
#else
  return exp2f(x);
#endif
}
__device__ __forceinline__ float flog2(float x){
#if __has_builtin(__builtin_amdgcn_logf)
  return __builtin_amdgcn_logf(x);
#else
  return log2f(x);
#endif
}
__device__ __forceinline__ unsigned enc_f(float f){
  unsigned u = __float_as_uint(f);
  return (u & 0x80000000u) ? ~u : (u | 0x80000000u);
}
__device__ __forceinline__ float dec_f(unsigned k){
  return __uint_as_float((k & 0x80000000u) ? (k ^ 0x80000000u) : ~k);
}

// Blocks 0..359: position_coeffs. Block 360: Gauss-Legendre + normalized
// Legendre (pre-scaled by log2e) -> PYs. (No Fourier table anymore: the
// compute kernel generates cos/sin by in-register rotation recurrence.)
__global__ __launch_bounds__(256) void fused_prep_kernel(
                              const float* __restrict__ focus, const float* __restrict__ embt,
                              const float* __restrict__ W, const int* __restrict__ tspec,
                              float* __restrict__ out, float* __restrict__ PYs){
  __shared__ double ak[RES_B + 1], bk[RES_B + 1];
  int blk = blockIdx.x;
  int t   = threadIdx.x;
  if (blk == 360){
    const double PI = 3.14159265358979323846;
    const double LOG2E = 1.4426950408889634074;
    if (t >= 2 && t <= RES_B){
      ak[t] = (2.0*t - 1.0) / (double)t;
      bk[t] = (t - 1.0) / (double)t;
    }
    __syncthreads();
    if (t < RES_B){
      int i = RES_B - 1 - t;                     // numpy leggauss: ascending nodes
      double x = cos(PI * (i + 0.75) / (RES_B + 0.5));
      for (int it = 0; it < 5; ++it){            // Newton on P_180
        double p0 = 1.0, p1 = x;
        for (int k = 2; k <= RES_B; ++k){
          double t1 = ak[k] * x;
          double pk = fma(t1, p1, -(bk[k] * p0));
          p0 = p1; p1 = pk;
        }
        x -= p1 * (x*x - 1.0) / ((double)RES_B * (x*p1 - p0));
      }
      double y = x;
      double sy = sqrt(fmax(1.0 - y*y, 0.0));
      double P[6][6];
      P[0][0] = 1.0;
      for (int m = 1; m < 6; ++m) P[m][m] = (2.0*m - 1.0)*sy*P[m-1][m-1];
      for (int m = 0; m < 5; ++m) P[m+1][m] = (2.0*m + 1.0)*y*P[m][m];
      for (int m = 0; m < 6; ++m)
        for (int l = m + 2; l < 6; ++l)
          P[l][m] = ((2.0*l - 1.0)*y*P[l-1][m] - (l + m - 1.0)*P[l-2][m]) / (double)(l - m);
      const double fact[11] = {1,1,2,6,24,120,720,5040,40320,362880,3628800};
      for (int l = 0; l < 6; ++l)
        for (int m = 0; m <= l; ++m){
          double K = sqrt((2.0*l + 1.0)/(4.0*PI)*fact[l-m]/fact[l+m]);
          double v = K * P[l][m] * LOG2E;
          if (m > 0) v *= sqrt(2.0);
          PYs[t*36 + l*6 + m] = (float)v;
        }
    }
  } else {
    int idx = blk * 256 + t;        // < 92160 always
    int i36 = idx % IDIM;
    int go  = idx / IDIM;
    int o   = go % (CH*RADII);
    int g   = go / (CH*RADII);
    int l   = (int)sqrtf((float)i36 + 0.5f);
    int mo  = i36 - l*l;
    int dim = 2*l + 1;
    const float* fp = focus + g*(MUL*IDIM) + MUL*l*l + mo;
    const float* ep = embt + tspec[g]*(MUL*6) + MUL*l;
    const float* wp = W + l*(MUL*80) + o;
    float s = 0.f;
    #pragma unroll 4
    for (int i = 0; i < MUL; ++i)
      s = fmaf(fp[i*dim] * ep[i], wp[i*80], s);
    out[idx] = s * 0.088388347648318447f;  // 1/sqrt(128)
  }
}

// LANES = BETA layout. Block = (g, r, alpha-chunk q), 192 threads (3 waves,
// lane -> beta = wave*64+lane; 12 idle). Per lane: its own tmp[44] in VGPRs
// (Legendre contraction done privately, once). Hot loop over 36 alpha-pairs:
// cos/sin(m*alpha) generated by in-register rotation recurrence (no Ftab, no
// LDS, no loads of any kind). h = C +/- S packed over channel pairs; sp/sm =
// sum_c 2^h. WRITE=0: per-graph max of sp/sm (atomicMax, exp-domain).
// WRITE=1: final logits = fma(log2(s), ln2, -log2(spmax)*ln2), staged in a
// per-wave LDS tile [64 beta][<=16 alpha] and flushed with lanes-along-alpha
// coalesced dword stores (avoids the stride-359 scatter of lane-beta writes).
template<int WRITE>
__global__ __launch_bounds__(192, 4) void compute_kernel(const float* __restrict__ coeffs,
                          const float* __restrict__ PYs,
                          float* __restrict__ out, unsigned* __restrict__ gmax){
  const float LN2 = 0.69314718055994531f;
  int blk = blockIdx.x;
  int q   = blk % NQ;
  int gr  = blk / NQ;                 // g*RADII + r
  int r   = gr % RADII;
  int g   = gr / RADII;
  int tid = threadIdx.x;
  int wave = tid >> 6, lane = tid & 63;
  int beta = wave*64 + lane;
  bool valid = beta < RES_B;
  int bc = valid ? beta : (RES_B - 1);

  extern __shared__ float smem[];
  float* cv   = smem;                 // [4][36]
  float* wred = smem + 144;           // [3]
  float* tile = smem + 148;           // [3 waves][2 sides][64][17]  (WRITE only)

  for (int v = tid; v < CH*IDIM; v += 192)
    cv[v] = coeffs[((g*CH + v/IDIM)*RADII + r)*IDIM + (v % IDIM)];
  __syncthreads();

  // per-lane Legendre row (16B-aligned: 36 floats = 144B stride)
  float pr[36];
  {
    const float4* p4 = reinterpret_cast<const float4*>(PYs + bc*36);
    #pragma unroll
    for (int j = 0; j < 9; ++j){
      float4 v = p4[j];
      pr[4*j] = v.x; pr[4*j+1] = v.y; pr[4*j+2] = v.z; pr[4*j+3] = v.w;
    }
  }
  // tmp[mm] for channel pairs (0,1) and (2,3); mm: 0=m0, 1..5=cos m, 6..10=sin m
  v2f tA[11], tB[11];
  #pragma unroll
  for (int mm = 0; mm < 11; ++mm){
    const int am = (mm == 0) ? 0 : (mm <= 5 ? mm : mm - 5);
    const int ii = (mm <= 5) ? am : -am;
    float s0 = 0.f, s1 = 0.f, s2 = 0.f, s3 = 0.f;
    #pragma unroll
    for (int l = am; l < 6; ++l){
      float p = pr[l*6 + am];
      int idx = l*l + l + ii;
      s0 = fmaf(cv[idx],       p, s0);
      s1 = fmaf(cv[36 + idx],  p, s1);
      s2 = fmaf(cv[72 + idx],  p, s2);
      s3 = fmaf(cv[108 + idx], p, s3);
    }
    tA[mm] = (v2f){s0, s1};
    tB[mm] = (v2f){s2, s3};
  }

  // trig state: cs/sn = cos/sin(m*alpha0); rc/rs = rotation by m*dA
  const float dA = (float)(6.2831853071795864769252867665590 / 359.0);
  float a0 = dA * (float)(q * PW);
  float cs[5], sn[5], rc[5], rs[5];
  #pragma unroll
  for (int m = 1; m <= 5; ++m){
    sincosf((float)m * a0, &sn[m-1], &cs[m-1]);
    sincosf((float)m * dA, &rs[m-1], &rc[m-1]);
  }

  float nsub = 0.f;
  if (WRITE) nsub = -flog2(dec_f(gmax[g])) * LN2;
  float mx0 = 0.f, mx1 = 0.f;
  int p0 = q * PW;
  float* twsp = tile + wave*(2*64*17);
  float* twsm = twsp + 64*17;

  auto body = [&](int ti){
    v2f C01 = tA[0], C23 = tB[0];
    #pragma unroll
    for (int m = 0; m < 5; ++m){
      v2f f = {cs[m], cs[m]};
      C01 = __builtin_elementwise_fma(tA[m+1], f, C01);
      C23 = __builtin_elementwise_fma(tB[m+1], f, C23);
    }
    v2f S01, S23;
    { v2f f = {sn[0], sn[0]}; S01 = tA[6]*f; S23 = tB[6]*f; }
    #pragma unroll
    for (int m = 1; m < 5; ++m){
      v2f f = {sn[m], sn[m]};
      S01 = __builtin_elementwise_fma(tA[6+m], f, S01);
      S23 = __builtin_elementwise_fma(tB[6+m], f, S23);
    }
    #pragma unroll
    for (int m = 0; m < 5; ++m){     // rotate alpha += dA
      float nc = fmaf(cs[m], rc[m], -(sn[m]*rs[m]));
      float ns = fmaf(sn[m], rc[m],   cs[m]*rs[m]);
      cs[m] = nc; sn[m] = ns;
    }
    v2f hp0 = C01 + S01, hp1 = C23 + S23;
    v2f hm0 = C01 - S01, hm1 = C23 - S23;
    float sp = (fexp2(hp0.x) + fexp2(hp0.y)) + (fexp2(hp1.x) + fexp2(hp1.y));
    float sm = (fexp2(hm0.x) + fexp2(hm0.y)) + (fexp2(hm1.x) + fexp2(hm1.y));
    if (WRITE){
      twsp[lane*17 + ti] = fmaf(flog2(sp), LN2, nsub);
      twsm[lane*17 + ti] = fmaf(flog2(sm), LN2, nsub);
    } else {
      mx0 = fmaxf(mx0, valid ? sp : 0.f);
      mx1 = fmaxf(mx1, valid ? sm : 0.f);
    }
  };

  auto flush = [&](int sb, int W, int lgW){   // tile cols [0,W) -> pairs p0+sb+c
    int rstep = 64 >> lgW;                    // rows per store inst
    int rl = lane >> lgW;                     // this lane's row offset
    int c  = lane & (W - 1);
    for (int rb = 0; rb < 64; rb += rstep){
      int rw = rb + rl;
      int b2 = wave*64 + rw;
      if (b2 < RES_B){
        size_t rowb = ((size_t)gr*RES_B + b2)*(size_t)RES_A;
        int pg = p0 + sb + c;
        out[rowb + pg] = twsp[rw*17 + c];
        if (pg) out[rowb + (RES_A - pg)] = twsm[rw*17 + c];
      }
    }
  };

  if (WRITE){
    for (int i = 0; i < 16; ++i) body(i);
    flush(0, 16, 4);
    for (int i = 0; i < 16; ++i) body(i);
    flush(16, 16, 4);
    for (int i = 0; i < 4; ++i) body(i);
    flush(32, 4, 2);
  } else {
    for (int i = 0; i < PW; ++i) body(0);
    float smax = fmaxf(mx0, mx1);
    #pragma unroll
    for (int off = 32; off > 0; off >>= 1)
      smax = fmaxf(smax, __shfl_xor(smax, off, 64));
    if (lane == 0) wred[wave] = smax;
    __syncthreads();
    if (tid == 0){
      float m = fmaxf(fmaxf(wred[0], wred[1]), wred[2]);
      atomicMax(gmax + g, enc_f(m));
    }
  }
}

extern "C" void kernel_launch(void* const* d_in, const int* in_sizes, int n_in,
                              void* d_out, int out_size, void* d_ws, size_t ws_size,
                              hipStream_t stream){
  const float* focus = (const float*)d_in[0];
  const float* embt  = (const float*)d_in[1];
  const float* W     = (const float*)d_in[2];
  const int*   tspec = (const int*)d_in[3];
  float* out = (float*)d_out;
  float* ws  = (float*)d_ws;
  unsigned* gmax = (unsigned*)d_ws;          // 32 slots (128 B)
  float* PYs  = ws + 32;                     // [180][36], 16B-aligned

  hipMemsetAsync(d_ws, 0, 128, stream);      // enc(sp>0) > 0, so 0 is identity
  fused_prep_kernel<<<361, 256, 0, stream>>>(focus, embt, W, tspec, out, PYs);
  float* logits = out + COEFF_N;
  size_t lds0 = 152 * sizeof(float);
  size_t lds1 = (148 + 3*2*64*17) * sizeof(float);
  compute_kernel<0><<<G_N*RADII*NQ, 192, lds0, stream>>>(out, PYs, logits, gmax);
  compute_kernel<1><<<G_N*RADII*NQ, 192, lds1, stream>>>(out, PYs, logits, gmax);
}

// Round 12
// 193.910 us; speedup vs baseline: 1.1710x; 1.1710x over previous
//
#include <hip/hip_runtime.h>

#define G_N    32
#define MUL    128
#define RADII  20
#define CH     4
#define RES_B  180
#define RES_A  359
#define IDIM   36
#define COEFF_N (G_N*CH*RADII*IDIM)   // 92160 = 360*256
#define NCHUNK 9
#define BCH_BLK 20                    // betas per block (4 waves)
#define BCH_W   5                     // betas per wave

typedef float v2f __attribute__((ext_vector_type(2)));

__device__ __forceinline__ float fexp2(float x){
#if __has_builtin(__builtin_amdgcn_exp2f)
  return __builtin_amdgcn_exp2f(x);     // raw v_exp_f32 (base-2), args bounded
#else
  return exp2f(x);
#endif
}
__device__ __forceinline__ float flog2(float x){
#if __has_builtin(__builtin_amdgcn_logf)
  return __builtin_amdgcn_logf(x);      // raw v_log_f32 (base-2)
#else
  return log2f(x);
#endif
}
// monotone float<->uint mapping for atomicMax on signed floats
__device__ __forceinline__ unsigned enc_f(float f){
  unsigned u = __float_as_uint(f);
  return (u & 0x80000000u) ? ~u : (u | 0x80000000u);
}
__device__ __forceinline__ float dec_f(unsigned k){
  return __uint_as_float((k & 0x80000000u) ? (k ^ 0x80000000u) : ~k);
}

// Blocks 0..359: position_coeffs. Block 360: table setup (Gauss-Legendre nodes,
// normalized Legendre * log2e -> PYs; Fourier rows -> Ftab).
__global__ __launch_bounds__(256) void fused_prep_kernel(
                              const float* __restrict__ focus, const float* __restrict__ embt,
                              const float* __restrict__ W, const int* __restrict__ tspec,
                              float* __restrict__ out,
                              float* __restrict__ PYs, float* __restrict__ Ftab){
  __shared__ double ak[RES_B + 1], bk[RES_B + 1];
  int blk = blockIdx.x;
  int t   = threadIdx.x;
  if (blk == 360){
    const double PI = 3.14159265358979323846;
    const double LOG2E = 1.4426950408889634074;
    if (t >= 2 && t <= RES_B){
      ak[t] = (2.0*t - 1.0) / (double)t;
      bk[t] = (t - 1.0) / (double)t;
    }
    __syncthreads();
    if (t < RES_B){
      int i = RES_B - 1 - t;                     // numpy leggauss: ascending nodes
      double x = cos(PI * (i + 0.75) / (RES_B + 0.5));
      for (int it = 0; it < 5; ++it){            // Newton on P_180
        double p0 = 1.0, p1 = x;
        for (int k = 2; k <= RES_B; ++k){
          double t1 = ak[k] * x;
          double pk = fma(t1, p1, -(bk[k] * p0));
          p0 = p1; p1 = pk;
        }
        x -= p1 * (x*x - 1.0) / ((double)RES_B * (x*p1 - p0));
      }
      double y = x;
      double sy = sqrt(fmax(1.0 - y*y, 0.0));
      double P[6][6];
      P[0][0] = 1.0;
      for (int m = 1; m < 6; ++m) P[m][m] = (2.0*m - 1.0)*sy*P[m-1][m-1];
      for (int m = 0; m < 5; ++m) P[m+1][m] = (2.0*m + 1.0)*y*P[m][m];
      for (int m = 0; m < 6; ++m)
        for (int l = m + 2; l < 6; ++l)
          P[l][m] = ((2.0*l - 1.0)*y*P[l-1][m] - (l + m - 1.0)*P[l-2][m]) / (double)(l - m);
      const double fact[11] = {1,1,2,6,24,120,720,5040,40320,362880,3628800};
      for (int l = 0; l < 6; ++l)
        for (int m = 0; m <= l; ++m){
          double K = sqrt((2.0*l + 1.0)/(4.0*PI)*fact[l-m]/fact[l+m]);
          double v = K * P[l][m] * LOG2E;
          if (m > 0) v *= sqrt(2.0);
          PYs[t*36 + l*6 + m] = (float)v;
        }
    }
    for (int a = t; a < RES_A; a += 256){
      double al = 2.0*PI*a/(double)RES_A;
      Ftab[a*12 + 0] = 1.0f;
      for (int m = 1; m <= 5; ++m){
        Ftab[a*12 + m]     = (float)cos(m*al);
        Ftab[a*12 + 5 + m] = (float)sin(m*al);
      }
      Ftab[a*12 + 11] = 0.f;
    }
  } else {
    int idx = blk * 256 + t;        // < 92160 always (360*256 exact)
    int i36 = idx % IDIM;
    int go  = idx / IDIM;           // g*80 + o, o = c*RADII + r
    int o   = go % (CH*RADII);
    int g   = go / (CH*RADII);
    int l   = (int)sqrtf((float)i36 + 0.5f);
    int mo  = i36 - l*l;            // m + l
    int dim = 2*l + 1;
    const float* fp = focus + g*(MUL*IDIM) + MUL*l*l + mo;
    const float* ep = embt + tspec[g]*(MUL*6) + MUL*l;
    const float* wp = W + l*(MUL*80) + o;
    float s = 0.f;
    #pragma unroll 4
    for (int i = 0; i < MUL; ++i)
      s = fmaf(fp[i*dim] * ep[i], wp[i*80], s);
    out[idx] = s * 0.088388347648318447f;  // 1/sqrt(128)
  }
}

// One block = (g, r, 20-beta chunk), 256 threads = 4 waves; wave w owns betas
// [w*5, w*5+5). NCHUNK=9 -> 5760 blocks = 22.5 waves/SIMD queued (vs 6.25 at
// NCHUNK=5): latency-hiding depth, small tail. Per-chunk totals (phase-1 work,
// LDS broadcast traffic, stores) are invariant under re-chunking.
// Phase 2: per beta each lane reads the 44 uniform floats once (broadcast
// ds_read_b128), evaluates THREE alpha-pairs p = lane+64k branch-free.
// WRITE=0: no stores; per-graph max of sp via atomicMax (exp-domain).
// WRITE=1: recompute, nontemporal-write final logits = fma(log2(sp), ln2, nsub).
template<int WRITE>
__global__ __launch_bounds__(256, 4) void compute_kernel(const float* __restrict__ coeffs,
                          const float* __restrict__ PYs, const float* __restrict__ Ftab,
                          float* __restrict__ out, unsigned* __restrict__ gmax){
  int blk   = blockIdx.x;
  int chunk = blk % NCHUNK;
  int gr    = blk / NCHUNK;                // g*RADII + r
  int r = gr % RADII;
  int g = gr / RADII;
  int tid  = threadIdx.x;
  int wave = tid >> 6, lane = tid & 63;
  int b0   = chunk * BCH_BLK;              // block beta base

  __shared__ float cv[CH][IDIM];
  __shared__ __align__(16) float tmpa[BCH_BLK][12][4];   // [beta][mm][channel]
  __shared__ float wred[4];

  for (int v = tid; v < CH*IDIM; v += 256){
    int c = v / IDIM, i = v % IDIM;
    cv[c][i] = coeffs[((g*CH + c)*RADII + r)*IDIM + i];
  }
  float nsub = 0.f;
  if (WRITE) nsub = -flog2(dec_f(gmax[g])) * 0.69314718055994531f;
  // 3 Fourier rows per lane: alpha = lane, lane+64, lane+128 (rows < 192 <= 358)
  float f0[11], f1[11], f2[11];
  {
    const float4* Fq = reinterpret_cast<const float4*>(Ftab);
    float4 a0 = Fq[lane*3],       a1 = Fq[lane*3+1],       a2 = Fq[lane*3+2];
    float4 b0v = Fq[(lane+64)*3], b1 = Fq[(lane+64)*3+1],  b2 = Fq[(lane+64)*3+2];
    float4 c0 = Fq[(lane+128)*3], c1 = Fq[(lane+128)*3+1], c2 = Fq[(lane+128)*3+2];
    f0[0]=a0.x; f0[1]=a0.y; f0[2]=a0.z; f0[3]=a0.w; f0[4]=a1.x; f0[5]=a1.y;
    f0[6]=a1.z; f0[7]=a1.w; f0[8]=a2.x; f0[9]=a2.y; f0[10]=a2.z;
    f1[0]=b0v.x; f1[1]=b0v.y; f1[2]=b0v.z; f1[3]=b0v.w; f1[4]=b1.x; f1[5]=b1.y;
    f1[6]=b1.z; f1[7]=b1.w; f1[8]=b2.x; f1[9]=b2.y; f1[10]=b2.z;
    f2[0]=c0.x; f2[1]=c0.y; f2[2]=c0.z; f2[3]=c0.w; f2[4]=c1.x; f2[5]=c1.y;
    f2[6]=c1.z; f2[7]=c1.w; f2[8]=c2.x; f2[9]=c2.y; f2[10]=c2.z;
  }
  __syncthreads();

  // phase 1: tmpa[b][mm][c] = sum_l cv[c][l^2+l+/-m] * PYs[b][l][|m|]
  for (int v = tid; v < BCH_BLK*44; v += 256){
    int bl = v / 44, cm = v % 44;
    int c = cm / 11, mm = cm % 11;
    int am, ii;
    if (mm == 0)      { am = 0;      ii = 0;        }
    else if (mm <= 5) { am = mm;     ii = mm;       }   // cos part: m > 0
    else              { am = mm - 5; ii = -(mm-5);  }   // sin part: m < 0
    const float* py = PYs + (b0 + bl)*36 + am;
    float s = 0.f;
    for (int l = am; l < 6; ++l)
      s = fmaf(cv[c][l*l + l + ii], py[l*6], s);
    tmpa[bl][mm][c] = s;
  }
  __syncthreads();

  const float LN2 = 0.69314718055994531f;
  float smx[3] = {0.f, 0.f, 0.f};          // per-k max accumulators (no serial chain)
  bool tail_ok = (lane < 52);              // k==2 validity
  float* row = out + ((size_t)gr*RES_B + b0 + wave*BCH_W)*RES_A;
  for (int bl = 0; bl < BCH_W; ++bl){
    const float4* tq = reinterpret_cast<const float4*>(&tmpa[wave*BCH_W + bl][0][0]);
    float4 q[11];
    #pragma unroll
    for (int mm = 0; mm < 11; ++mm) q[mm] = tq[mm];   // 11x ds_read_b128 broadcast
    #pragma unroll
    for (int k = 0; k < 3; ++k){
      const float* fr = (k == 0) ? f0 : (k == 1) ? f1 : f2;
      int p = lane + 64*k;
      #define PK(i) (v2f){q[i].x, q[i].y}
      #define PK2(i) (v2f){q[i].z, q[i].w}
      #define FS(i) (v2f){fr[i], fr[i]}
      v2f ca0 = __builtin_elementwise_fma(PK(1), FS(1), PK(0));
      v2f ca1 = __builtin_elementwise_fma(PK2(1), FS(1), PK2(0));
      v2f cb0 = __builtin_elementwise_fma(PK(3), FS(3), PK(2) * FS(2));
      v2f cb1 = __builtin_elementwise_fma(PK2(3), FS(3), PK2(2) * FS(2));
      v2f cc0 = __builtin_elementwise_fma(PK(5), FS(5), PK(4) * FS(4));
      v2f cc1 = __builtin_elementwise_fma(PK2(5), FS(5), PK2(4) * FS(4));
      v2f C01 = (ca0 + cb0) + cc0;
      v2f C23 = (ca1 + cb1) + cc1;
      v2f sa0 = __builtin_elementwise_fma(PK(7), FS(7), PK(6) * FS(6));
      v2f sa1 = __builtin_elementwise_fma(PK2(7), FS(7), PK2(6) * FS(6));
      v2f sb0 = __builtin_elementwise_fma(PK(9), FS(9), PK(8) * FS(8));
      v2f sb1 = __builtin_elementwise_fma(PK2(9), FS(9), PK2(8) * FS(8));
      v2f S01 = (sa0 + sb0) + PK(10) * FS(10);
      v2f S23 = (sa1 + sb1) + PK2(10) * FS(10);
      #undef PK
      #undef PK2
      #undef FS
      v2f hp01 = C01 + S01, hp23 = C23 + S23;
      v2f hm01 = C01 - S01, hm23 = C23 - S23;
      float sp = (fexp2(hp01.x) + fexp2(hp01.y)) + (fexp2(hp23.x) + fexp2(hp23.y));
      float sm = (fexp2(hm01.x) + fexp2(hm01.y)) + (fexp2(hm23.x) + fexp2(hm23.y));
      if (WRITE){
        if (k < 2 || tail_ok){               // k<2 folds at compile time
          __builtin_nontemporal_store(fmaf(flog2(sp), LN2, nsub), &row[p]);
          if (p) __builtin_nontemporal_store(fmaf(flog2(sm), LN2, nsub), &row[359 - p]);
        }
      } else {
        float mx = fmaxf(sp, sm);
        smx[k] = fmaxf(smx[k], (k < 2 || tail_ok) ? mx : 0.f);
      }
    }
    row += RES_A;
  }
  if (!WRITE){
    float smax = fmaxf(fmaxf(smx[0], smx[1]), smx[2]);
    #pragma unroll
    for (int off = 32; off > 0; off >>= 1)
      smax = fmaxf(smax, __shfl_xor(smax, off, 64));
    if (lane == 0) wred[wave] = smax;
    __syncthreads();
    if (tid == 0){
      float m = fmaxf(fmaxf(wred[0], wred[1]), fmaxf(wred[2], wred[3]));
      atomicMax(gmax + g, enc_f(m));         // max of sp (exp-domain)
    }
  }
}

extern "C" void kernel_launch(void* const* d_in, const int* in_sizes, int n_in,
                              void* d_out, int out_size, void* d_ws, size_t ws_size,
                              hipStream_t stream){
  const float* focus = (const float*)d_in[0];
  const float* embt  = (const float*)d_in[1];
  const float* W     = (const float*)d_in[2];
  const int*   tspec = (const int*)d_in[3];
  float* out = (float*)d_out;
  float* ws  = (float*)d_ws;
  unsigned* gmax = (unsigned*)d_ws;          // 32 slots (128 B)
  float* PYs  = ws + 32;                     // [180][36]
  float* Ftab = ws + 32 + RES_B*36;          // [359][12], 16B-aligned

  hipMemsetAsync(d_ws, 0, 128, stream);      // enc(sp>0) > 0, so 0 is identity
  fused_prep_kernel<<<361, 256, 0, stream>>>(focus, embt, W, tspec, out, PYs, Ftab);
  float* logits = out + COEFF_N;
  compute_kernel<0><<<G_N*RADII*NCHUNK, 256, 0, stream>>>(out, PYs, Ftab, logits, gmax);
  compute_kernel<1><<<G_N*RADII*NCHUNK, 256, 0, stream>>>(out, PYs, Ftab, logits, gmax);
}

// Round 13
// 162.991 us; speedup vs baseline: 1.3931x; 1.1897x over previous
//
#include <hip/hip_runtime.h>

#define G_N    32
#define MUL    128
#define RADII  20
#define CH     4
#define RES_B  180
#define RES_A  359
#define IDIM   36
#define COEFF_N (G_N*CH*RADII*IDIM)   // 92160 = 360*256
#define NCHUNK 5
#define BCH_BLK 36                    // betas per block (4 waves)
#define BCH_W   9                     // betas per wave

typedef float v2f __attribute__((ext_vector_type(2)));

__device__ __forceinline__ float fexp2(float x){
#if __has_builtin(__builtin_amdgcn_exp2f)
  return __builtin_amdgcn_exp2f(x);     // raw v_exp_f32 (base-2), args bounded
#else
  return exp2f(x);
#endif
}
__device__ __forceinline__ float flog2(float x){
#if __has_builtin(__builtin_amdgcn_logf)
  return __builtin_amdgcn_logf(x);      // raw v_log_f32 (base-2)
#else
  return log2f(x);
#endif
}
__device__ __forceinline__ unsigned enc_f(float f){
  unsigned u = __float_as_uint(f);
  return (u & 0x80000000u) ? ~u : (u | 0x80000000u);
}
__device__ __forceinline__ float dec_f(unsigned k){
  return __uint_as_float((k & 0x80000000u) ? (k ^ 0x80000000u) : ~k);
}

// Blocks 0..359: position_coeffs. Block 360: table setup.
__global__ __launch_bounds__(256) void fused_prep_kernel(
                              const float* __restrict__ focus, const float* __restrict__ embt,
                              const float* __restrict__ W, const int* __restrict__ tspec,
                              float* __restrict__ out,
                              float* __restrict__ PYs, float* __restrict__ Ftab){
  __shared__ double ak[RES_B + 1], bk[RES_B + 1];
  int blk = blockIdx.x;
  int t   = threadIdx.x;
  if (blk == 360){
    const double PI = 3.14159265358979323846;
    const double LOG2E = 1.4426950408889634074;
    if (t >= 2 && t <= RES_B){
      ak[t] = (2.0*t - 1.0) / (double)t;
      bk[t] = (t - 1.0) / (double)t;
    }
    __syncthreads();
    if (t < RES_B){
      int i = RES_B - 1 - t;                     // numpy leggauss: ascending nodes
      double x = cos(PI * (i + 0.75) / (RES_B + 0.5));
      for (int it = 0; it < 3; ++it){            // Newton on P_180 (guess 1e-4 -> 2 iters suffice)
        double p0 = 1.0, p1 = x;
        for (int k = 2; k <= RES_B; ++k){
          double t1 = ak[k] * x;
          double pk = fma(t1, p1, -(bk[k] * p0));
          p0 = p1; p1 = pk;
        }
        x -= p1 * (x*x - 1.0) / ((double)RES_B * (x*p1 - p0));
      }
      double y = x;
      double sy = sqrt(fmax(1.0 - y*y, 0.0));
      double P[6][6];
      P[0][0] = 1.0;
      for (int m = 1; m < 6; ++m) P[m][m] = (2.0*m - 1.0)*sy*P[m-1][m-1];
      for (int m = 0; m < 5; ++m) P[m+1][m] = (2.0*m + 1.0)*y*P[m][m];
      for (int m = 0; m < 6; ++m)
        for (int l = m + 2; l < 6; ++l)
          P[l][m] = ((2.0*l - 1.0)*y*P[l-1][m] - (l + m - 1.0)*P[l-2][m]) / (double)(l - m);
      const double fact[11] = {1,1,2,6,24,120,720,5040,40320,362880,3628800};
      for (int l = 0; l < 6; ++l)
        for (int m = 0; m <= l; ++m){
          double K = sqrt((2.0*l + 1.0)/(4.0*PI)*fact[l-m]/fact[l+m]);
          double v = K * P[l][m] * LOG2E;
          if (m > 0) v *= sqrt(2.0);
          PYs[t*36 + l*6 + m] = (float)v;
        }
    }
    for (int a = t; a < RES_A; a += 256){
      double al = 2.0*PI*a/(double)RES_A;
      Ftab[a*12 + 0] = 1.0f;
      for (int m = 1; m <= 5; ++m){
        Ftab[a*12 + m]     = (float)cos(m*al);
        Ftab[a*12 + 5 + m] = (float)sin(m*al);
      }
      Ftab[a*12 + 11] = 0.f;
    }
  } else {
    int idx = blk * 256 + t;        // < 92160 always (360*256 exact)
    int i36 = idx % IDIM;
    int go  = idx / IDIM;           // g*80 + o, o = c*RADII + r
    int o   = go % (CH*RADII);
    int g   = go / (CH*RADII);
    int l   = (int)sqrtf((float)i36 + 0.5f);
    int mo  = i36 - l*l;            // m + l
    int dim = 2*l + 1;
    const float* fp = focus + g*(MUL*IDIM) + MUL*l*l + mo;
    const float* ep = embt + tspec[g]*(MUL*6) + MUL*l;
    const float* wp = W + l*(MUL*80) + o;
    float s = 0.f;
    #pragma unroll 4
    for (int i = 0; i < MUL; ++i)
      s = fmaf(fp[i*dim] * ep[i], wp[i*80], s);
    out[idx] = s * 0.088388347648318447f;  // 1/sqrt(128)
  }
}

// One block = (g, r, 36-beta chunk), 256 threads = 4 waves; wave w owns betas
// [w*9, w*9+9). Phase 2 is MM-MAJOR: each tq[mm] ds_read_b128 is applied to
// ALL THREE k-accumulator sets immediately, then dies. Source-level q lifetime
// = one mm => the compiler needs ~90 VGPRs (not ~100+) and emits exactly 11
// LDS reads per beta (the old k-major source forced re-reads at VGPR=64:
// ~33 reads/beta = 3x LDS traffic + 3x latency exposure -- the 75us plateau).
// 12 independent FMA chains (3k x 4 halves) for latency hiding.
// WRITE=0: no stores; per-graph max of sp/sm via atomicMax (exp-domain;
//   k=2 lanes>=52 produce exact duplicates of valid alphas -- harmless in max).
// WRITE=1: recompute; write final logits = fma(log2(s), ln2, -log2(smax)*ln2);
//   stores guarded (k<2 || lane<52) for determinism.
template<int WRITE>
__global__ __launch_bounds__(256, 4) void compute_kernel(const float* __restrict__ coeffs,
                          const float* __restrict__ PYs, const float* __restrict__ Ftab,
                          float* __restrict__ out, unsigned* __restrict__ gmax){
  int blk   = blockIdx.x;
  int chunk = blk % NCHUNK;
  int gr    = blk / NCHUNK;                // g*RADII + r
  int r = gr % RADII;
  int g = gr / RADII;
  int tid  = threadIdx.x;
  int wave = tid >> 6, lane = tid & 63;
  int b0   = chunk * BCH_BLK;              // block beta base

  __shared__ float cv[CH][IDIM];
  __shared__ __align__(16) float tmpa[BCH_BLK][12][4];   // [beta][mm][channel]
  __shared__ float wred[4];

  for (int v = tid; v < CH*IDIM; v += 256){
    int c = v / IDIM, i = v % IDIM;
    cv[c][i] = coeffs[((g*CH + c)*RADII + r)*IDIM + i];
  }
  float nsub = 0.f;
  if (WRITE) nsub = -flog2(dec_f(gmax[g])) * 0.69314718055994531f;
  // 3 Fourier rows per lane: alpha = lane, lane+64, lane+128 (rows < 192 <= 358)
  float f0[11], f1[11], f2[11];
  {
    const float4* Fq = reinterpret_cast<const float4*>(Ftab);
    float4 a0 = Fq[lane*3],       a1 = Fq[lane*3+1],       a2 = Fq[lane*3+2];
    float4 b0v = Fq[(lane+64)*3], b1 = Fq[(lane+64)*3+1],  b2 = Fq[(lane+64)*3+2];
    float4 c0 = Fq[(lane+128)*3], c1 = Fq[(lane+128)*3+1], c2 = Fq[(lane+128)*3+2];
    f0[0]=a0.x; f0[1]=a0.y; f0[2]=a0.z; f0[3]=a0.w; f0[4]=a1.x; f0[5]=a1.y;
    f0[6]=a1.z; f0[7]=a1.w; f0[8]=a2.x; f0[9]=a2.y; f0[10]=a2.z;
    f1[0]=b0v.x; f1[1]=b0v.y; f1[2]=b0v.z; f1[3]=b0v.w; f1[4]=b1.x; f1[5]=b1.y;
    f1[6]=b1.z; f1[7]=b1.w; f1[8]=b2.x; f1[9]=b2.y; f1[10]=b2.z;
    f2[0]=c0.x; f2[1]=c0.y; f2[2]=c0.z; f2[3]=c0.w; f2[4]=c1.x; f2[5]=c1.y;
    f2[6]=c1.z; f2[7]=c1.w; f2[8]=c2.x; f2[9]=c2.y; f2[10]=c2.z;
  }
  __syncthreads();

  // phase 1: tmpa[b][mm][c] = sum_l cv[c][l^2+l+/-m] * PYs[b][l][|m|]
  for (int v = tid; v < BCH_BLK*44; v += 256){
    int bl = v / 44, cm = v % 44;
    int c = cm / 11, mm = cm % 11;
    int am, ii;
    if (mm == 0)      { am = 0;      ii = 0;        }
    else if (mm <= 5) { am = mm;     ii = mm;       }   // cos part: m > 0
    else              { am = mm - 5; ii = -(mm-5);  }   // sin part: m < 0
    const float* py = PYs + (b0 + bl)*36 + am;
    float s = 0.f;
    for (int l = am; l < 6; ++l)
      s = fmaf(cv[c][l*l + l + ii], py[l*6], s);
    tmpa[bl][mm][c] = s;
  }
  __syncthreads();

  const float LN2 = 0.69314718055994531f;
  float smx[3] = {0.f, 0.f, 0.f};
  bool tail_ok = (lane < 52);
  float* row = out + ((size_t)gr*RES_B + b0 + wave*BCH_W)*RES_A;
  for (int bl = 0; bl < BCH_W; ++bl){
    const float4* tq = reinterpret_cast<const float4*>(&tmpa[wave*BCH_W + bl][0][0]);
    v2f C01[3], C23[3], S01[3], S23[3];
    {
      float4 qv = tq[0];
      v2f a = {qv.x, qv.y}, b = {qv.z, qv.w};
      #pragma unroll
      for (int k = 0; k < 3; ++k){ C01[k] = a; C23[k] = b; }   // fr[0]==1
    }
    #pragma unroll
    for (int mm = 1; mm <= 5; ++mm){
      float4 qv = tq[mm];
      v2f a = {qv.x, qv.y}, b = {qv.z, qv.w};
      C01[0] = __builtin_elementwise_fma(a, (v2f){f0[mm], f0[mm]}, C01[0]);
      C23[0] = __builtin_elementwise_fma(b, (v2f){f0[mm], f0[mm]}, C23[0]);
      C01[1] = __builtin_elementwise_fma(a, (v2f){f1[mm], f1[mm]}, C01[1]);
      C23[1] = __builtin_elementwise_fma(b, (v2f){f1[mm], f1[mm]}, C23[1]);
      C01[2] = __builtin_elementwise_fma(a, (v2f){f2[mm], f2[mm]}, C01[2]);
      C23[2] = __builtin_elementwise_fma(b, (v2f){f2[mm], f2[mm]}, C23[2]);
    }
    {
      float4 qv = tq[6];
      v2f a = {qv.x, qv.y}, b = {qv.z, qv.w};
      S01[0] = a * (v2f){f0[6], f0[6]};  S23[0] = b * (v2f){f0[6], f0[6]};
      S01[1] = a * (v2f){f1[6], f1[6]};  S23[1] = b * (v2f){f1[6], f1[6]};
      S01[2] = a * (v2f){f2[6], f2[6]};  S23[2] = b * (v2f){f2[6], f2[6]};
    }
    #pragma unroll
    for (int mm = 7; mm <= 10; ++mm){
      float4 qv = tq[mm];
      v2f a = {qv.x, qv.y}, b = {qv.z, qv.w};
      S01[0] = __builtin_elementwise_fma(a, (v2f){f0[mm], f0[mm]}, S01[0]);
      S23[0] = __builtin_elementwise_fma(b, (v2f){f0[mm], f0[mm]}, S23[0]);
      S01[1] = __builtin_elementwise_fma(a, (v2f){f1[mm], f1[mm]}, S01[1]);
      S23[1] = __builtin_elementwise_fma(b, (v2f){f1[mm], f1[mm]}, S23[1]);
      S01[2] = __builtin_elementwise_fma(a, (v2f){f2[mm], f2[mm]}, S01[2]);
      S23[2] = __builtin_elementwise_fma(b, (v2f){f2[mm], f2[mm]}, S23[2]);
    }
    #pragma unroll
    for (int k = 0; k < 3; ++k){
      v2f hp0 = C01[k] + S01[k], hp1 = C23[k] + S23[k];
      v2f hm0 = C01[k] - S01[k], hm1 = C23[k] - S23[k];
      float sp = (fexp2(hp0.x) + fexp2(hp0.y)) + (fexp2(hp1.x) + fexp2(hp1.y));
      float sm = (fexp2(hm0.x) + fexp2(hm0.y)) + (fexp2(hm1.x) + fexp2(hm1.y));
      if (WRITE){
        if (k < 2 || tail_ok){
          int p = lane + 64*k;
          row[p] = fmaf(flog2(sp), LN2, nsub);
          if (p) row[359 - p] = fmaf(flog2(sm), LN2, nsub);
        }
      } else {
        smx[k] = fmaxf(smx[k], fmaxf(sp, sm));   // k2 tail lanes: exact duplicates, harmless
      }
    }
    row += RES_A;
  }
  if (!WRITE){
    float smax = fmaxf(fmaxf(smx[0], smx[1]), smx[2]);
    #pragma unroll
    for (int off = 32; off > 0; off >>= 1)
      smax = fmaxf(smax, __shfl_xor(smax, off, 64));
    if (lane == 0) wred[wave] = smax;
    __syncthreads();
    if (tid == 0){
      float m = fmaxf(fmaxf(wred[0], wred[1]), fmaxf(wred[2], wred[3]));
      atomicMax(gmax + g, enc_f(m));         // max of sp (exp-domain)
    }
  }
}

extern "C" void kernel_launch(void* const* d_in, const int* in_sizes, int n_in,
                              void* d_out, int out_size, void* d_ws, size_t ws_size,
                              hipStream_t stream){
  const float* focus = (const float*)d_in[0];
  const float* embt  = (const float*)d_in[1];
  const float* W     = (const float*)d_in[2];
  const int*   tspec = (const int*)d_in[3];
  float* out = (float*)d_out;
  float* ws  = (float*)d_ws;
  unsigned* gmax = (unsigned*)d_ws;          // 32 slots (128 B)
  float* PYs  = ws + 32;                     // [180][36]
  float* Ftab = ws + 32 + RES_B*36;          // [359][12], 16B-aligned

  hipMemsetAsync(d_ws, 0, 128, stream);      // enc(sp>0) > 0, so 0 is identity
  fused_prep_kernel<<<361, 256, 0, stream>>>(focus, embt, W, tspec, out, PYs, Ftab);
  float* logits = out + COEFF_N;
  compute_kernel<0><<<G_N*RADII*NCHUNK, 256, 0, stream>>>(out, PYs, Ftab, logits, gmax);
  compute_kernel<1><<<G_N*RADII*NCHUNK, 256, 0, stream>>>(out, PYs, Ftab, logits, gmax);
}